// Round 6
// baseline (594.354 us; speedup 1.0000x reference)
//
#include <hip/hip_runtime.h>
#include <math.h>

#define N_NODES 50000
#define N_EDGES 800000
#define NFEAT   512
#define NHID    64
#define NCLASS  40

// ---------------------------------------------------------------------------
// CSR build: histogram of dst -> exclusive scan -> scatter of edge ids into
// perm[], so SpMM is a per-row gather-reduce with NO fp atomics.
// ---------------------------------------------------------------------------

__global__ void zero_kernel(int* __restrict__ p, int n) {
    int i = blockIdx.x * blockDim.x + threadIdx.x;
    if (i < n) p[i] = 0;
}

__global__ void hist_kernel(const int* __restrict__ dst, int* __restrict__ counts) {
    int i = blockIdx.x * blockDim.x + threadIdx.x;
    if (i < N_EDGES) atomicAdd(&counts[dst[i]], 1);
}

__global__ __launch_bounds__(1024) void scan_kernel(int* __restrict__ cnt_next,
                                                    int* __restrict__ row_off) {
    __shared__ int lds[1024];
    const int t  = threadIdx.x;
    const int CH = (N_NODES + 1023) / 1024;      // 49
    const int lo = t * CH;
    const int hi = (lo + CH < N_NODES) ? lo + CH : N_NODES;

    int s = 0;
    for (int i = lo; i < hi; ++i) s += cnt_next[i];
    lds[t] = s;
    __syncthreads();
    for (int off = 1; off < 1024; off <<= 1) {
        int v = (t >= off) ? lds[t - off] : 0;
        __syncthreads();
        lds[t] += v;
        __syncthreads();
    }
    int excl  = lds[t] - s;
    int total = lds[1023];

    int run = excl;
    for (int i = lo; i < hi; ++i) {
        int c = cnt_next[i];          // read before overwrite (same buffer)
        row_off[i]  = run;
        cnt_next[i] = run;            // becomes the scatter cursor
        run += c;
    }
    if (t == 0) row_off[N_NODES] = total;
}

__global__ void scatter_kernel(const int* __restrict__ dst,
                               int* __restrict__ cursor,
                               int* __restrict__ perm) {
    int i = blockIdx.x * blockDim.x + threadIdx.x;
    if (i < N_EDGES) {
        int p = atomicAdd(&cursor[dst[i]], 1);
        perm[p] = i;
    }
}

// ---------------------------------------------------------------------------
// GEMM1: xw = x @ W1.  [50000,512] x [512,64].
// Block = 256 threads (4 waves), block tile = 64 rows x 64 cols.
// Lane tile = 4 rows x 4 cols, acc carried across all K (single store).
// W1 chunk (128 k) in LDS, swizzled for conflict-free ds_read_b128 reads:
//   read slot(k0, c, i16) = k0*64 + c*16 + i16  (holds col 4*i16 + c)
// Staging WRITES are linear (lane-consecutive 16B -> 2-way, free); the
// column held by slot s is the inverse swizzle c = 4*(s&15) + (s>>4).
// x is read from global as 16B broadcast loads with an explicit
// distance-1 software prefetch (next 4-k group loaded while FMA-ing the
// current one, including across the chunk barrier -- x loads have no LDS
// dependency). __launch_bounds__(256,3) gives the register budget (~170)
// needed to keep ~8 loads in flight; at 64 VGPRs (round 5) the compiler
// could not pipeline and the kernel ran at 30% VALUBusy, latency-bound.
// ---------------------------------------------------------------------------
__global__ __launch_bounds__(256, 3) void gemm1_kernel(const float* __restrict__ x,
                                                       const float* __restrict__ W1,
                                                       float* __restrict__ xw) {
    __shared__ float4 wlds[32 * 64];              // 32 KB per 128-k chunk
    const int tid  = threadIdx.x;
    const int lane = tid & 63;
    const int i16  = lane & 15;                   // col group: cols 4*i16..+3
    const int rg   = lane >> 4;                   // row group within wave (0..3)
    const int wave = tid >> 6;                    // 0..3

    const int block_row0 = blockIdx.x * 64;
    const int wave_row0  = block_row0 + wave * 16;

    const float* xb[4];
    int rows[4];
#pragma unroll
    for (int r = 0; r < 4; ++r) {
        int row = wave_row0 + rg * 4 + r;
        rows[r] = row;
        int rc = row < N_NODES ? row : N_NODES - 1;
        xb[r] = x + (size_t)rc * NFEAT;
    }

    float acc[4][4];
#pragma unroll
    for (int r = 0; r < 4; ++r)
#pragma unroll
        for (int c = 0; c < 4; ++c) acc[r][c] = 0.f;

    // Prime the x prefetch pipeline (chunk 0, k0 = 0).
    float4 xv[4];
#pragma unroll
    for (int r = 0; r < 4; ++r)
        xv[r] = *reinterpret_cast<const float4*>(xb[r]);

    for (int chunk = 0; chunk < 4; ++chunk) {
        __syncthreads();                          // previous chunk's reads done
        // Stage W1[kb..kb+127][0..63] -> wlds. Linear slot writes
        // (conflict-free); col derived from slot by inverse swizzle.
        for (int idx = tid; idx < 32 * 64; idx += 256) {
            int k0  = idx >> 6;
            int s   = idx & 63;
            int col = 4 * (s & 15) + (s >> 4);
            int kb  = chunk * 128 + 4 * k0;
            float4 v;
            v.x = W1[(kb + 0) * NHID + col];
            v.y = W1[(kb + 1) * NHID + col];
            v.z = W1[(kb + 2) * NHID + col];
            v.w = W1[(kb + 3) * NHID + col];
            wlds[idx] = v;
        }
        __syncthreads();

        const int kb = chunk * 128;
#pragma unroll 4
        for (int k0 = 0; k0 < 32; ++k0) {
            // Prefetch next 4-k group (or next chunk's first group).
            int knext = (k0 < 31) ? (kb + 4 * k0 + 4)
                                  : ((chunk < 3) ? (chunk + 1) * 128 : 0);
            float4 xn[4];
#pragma unroll
            for (int r = 0; r < 4; ++r)
                xn[r] = *reinterpret_cast<const float4*>(xb[r] + knext);

            float4 wv[4];
#pragma unroll
            for (int c = 0; c < 4; ++c)
                wv[c] = wlds[k0 * 64 + c * 16 + i16];
#pragma unroll
            for (int r = 0; r < 4; ++r) {
#pragma unroll
                for (int c = 0; c < 4; ++c) {
                    acc[r][c] = fmaf(xv[r].x, wv[c].x,
                                fmaf(xv[r].y, wv[c].y,
                                fmaf(xv[r].z, wv[c].z,
                                fmaf(xv[r].w, wv[c].w, acc[r][c]))));
                }
            }
#pragma unroll
            for (int r = 0; r < 4; ++r) xv[r] = xn[r];
        }
    }

    // Epilogue: one float4 store per row (cols 4*i16..4*i16+3 consecutive).
#pragma unroll
    for (int r = 0; r < 4; ++r) {
        if (rows[r] < N_NODES) {
            float4 o; o.x = acc[r][0]; o.y = acc[r][1]; o.z = acc[r][2]; o.w = acc[r][3];
            *reinterpret_cast<float4*>(&xw[(size_t)rows[r] * NHID + 4 * i16]) = o;
        }
    }
}

// ---------------------------------------------------------------------------
// SpMM1 + bias + relu: h[r] = relu(sum_e val_e * xw[src_e] + b1)
// Wave per row, lane = feature (64). 4-way unrolled gather for ILP.
// ---------------------------------------------------------------------------
__global__ void spmm1_kernel(const float* __restrict__ xw,
                             const float* __restrict__ adj_vals,
                             const int* __restrict__ src,
                             const int* __restrict__ perm,
                             const int* __restrict__ row_off,
                             const float* __restrict__ b1,
                             float* __restrict__ h) {
    const int lane = threadIdx.x & 63;
    const int row  = blockIdx.x * 4 + (threadIdx.x >> 6);
    if (row >= N_NODES) return;
    const int lo = row_off[row], hi = row_off[row + 1];
    float acc = 0.f;
    int i = lo;
    for (; i + 3 < hi; i += 4) {
        int e0 = perm[i], e1 = perm[i+1], e2 = perm[i+2], e3 = perm[i+3];
        float v0 = adj_vals[e0], v1 = adj_vals[e1], v2 = adj_vals[e2], v3 = adj_vals[e3];
        int s0 = src[e0], s1 = src[e1], s2 = src[e2], s3 = src[e3];
        float f0 = xw[s0*NHID+lane], f1 = xw[s1*NHID+lane];
        float f2 = xw[s2*NHID+lane], f3 = xw[s3*NHID+lane];
        acc += v0*f0; acc += v1*f1; acc += v2*f2; acc += v3*f3;
    }
    for (; i < hi; ++i) {
        int e = perm[i];
        acc += adj_vals[e] * xw[src[e]*NHID + lane];
    }
    h[(size_t)row * NHID + lane] = fmaxf(acc + b1[lane], 0.f);
}

// ---------------------------------------------------------------------------
// GEMM2: hw = h @ W2. [50000,64] x [64,40]. Broadcast scheme, W2 in LDS.
// ---------------------------------------------------------------------------
__global__ void gemm2_kernel(const float* __restrict__ h,
                             const float* __restrict__ W2,
                             float* __restrict__ hw) {
    __shared__ float4 wlds[(NHID / 4) * NCLASS];   // 16*40 float4 = 10 KB
    const int tid = threadIdx.x;
    for (int idx = tid; idx < (NHID / 4) * NCLASS; idx += 256) {
        int k0 = idx / NCLASS, c = idx % NCLASS;
        float4 v;
        v.x = W2[(4*k0 + 0) * NCLASS + c];
        v.y = W2[(4*k0 + 1) * NCLASS + c];
        v.z = W2[(4*k0 + 2) * NCLASS + c];
        v.w = W2[(4*k0 + 3) * NCLASS + c];
        wlds[idx] = v;
    }
    __syncthreads();

    const int R = 8;
    const int lane = tid & 63;
    const int wid  = blockIdx.x * 4 + (tid >> 6);
    const int ngroups = (N_NODES + R - 1) / R;
    if (wid >= ngroups) return;
    const int row0 = wid * R;
    const int cl = (lane < NCLASS) ? lane : (NCLASS - 1);
    const bool active = lane < NCLASS;

    float acc[R];
    const float* hp[R];
#pragma unroll
    for (int r = 0; r < R; ++r) {
        acc[r] = 0.f;
        int row = row0 + r; if (row > N_NODES - 1) row = N_NODES - 1;
        hp[r] = h + (size_t)row * NHID;
    }
#pragma unroll
    for (int k0 = 0; k0 < NHID / 4; ++k0) {
        float4 w4 = wlds[k0 * NCLASS + cl];
#pragma unroll
        for (int r = 0; r < R; ++r) {
            float4 hv = *reinterpret_cast<const float4*>(hp[r] + 4 * k0);
            acc[r] = fmaf(hv.x, w4.x,
                     fmaf(hv.y, w4.y,
                     fmaf(hv.z, w4.z,
                     fmaf(hv.w, w4.w, acc[r]))));
        }
    }
#pragma unroll
    for (int r = 0; r < R; ++r) {
        int row = row0 + r;
        if (active && row < N_NODES) hw[(size_t)row * NCLASS + lane] = acc[r];
    }
}

// ---------------------------------------------------------------------------
// SpMM2 + b2 + log_softmax, fused. Wave per row, lanes 0..39 = classes.
// ---------------------------------------------------------------------------
__global__ void spmm2_lsm_kernel(const float* __restrict__ hw,
                                 const float* __restrict__ adj_vals,
                                 const int* __restrict__ src,
                                 const int* __restrict__ perm,
                                 const int* __restrict__ row_off,
                                 const float* __restrict__ b2,
                                 float* __restrict__ out) {
    const int lane = threadIdx.x & 63;
    const int row  = blockIdx.x * 4 + (threadIdx.x >> 6);
    if (row >= N_NODES) return;
    const bool active = lane < NCLASS;
    const int cl = active ? lane : (NCLASS - 1);
    const int lo = row_off[row], hi = row_off[row + 1];
    float acc = 0.f;
    int i = lo;
    for (; i + 3 < hi; i += 4) {
        int e0 = perm[i], e1 = perm[i+1], e2 = perm[i+2], e3 = perm[i+3];
        float v0 = adj_vals[e0], v1 = adj_vals[e1], v2 = adj_vals[e2], v3 = adj_vals[e3];
        int s0 = src[e0], s1 = src[e1], s2 = src[e2], s3 = src[e3];
        float f0 = hw[s0*NCLASS+cl], f1 = hw[s1*NCLASS+cl];
        float f2 = hw[s2*NCLASS+cl], f3 = hw[s3*NCLASS+cl];
        acc += v0*f0; acc += v1*f1; acc += v2*f2; acc += v3*f3;
    }
    for (; i < hi; ++i) {
        int e = perm[i];
        acc += adj_vals[e] * hw[src[e]*NCLASS + cl];
    }
    float logit = acc + b2[cl];
    float m = active ? logit : -INFINITY;
#pragma unroll
    for (int o = 32; o > 0; o >>= 1) m = fmaxf(m, __shfl_xor(m, o));
    float ex = active ? expf(logit - m) : 0.f;
    float ssum = ex;
#pragma unroll
    for (int o = 32; o > 0; o >>= 1) ssum += __shfl_xor(ssum, o);
    if (active) out[(size_t)row * NCLASS + lane] = logit - m - logf(ssum);
}

// ---------------------------------------------------------------------------

extern "C" void kernel_launch(void* const* d_in, const int* in_sizes, int n_in,
                              void* d_out, int out_size, void* d_ws, size_t ws_size,
                              hipStream_t stream) {
    const float* x        = (const float*)d_in[0];
    const float* adj_vals = (const float*)d_in[1];
    const float* W1       = (const float*)d_in[2];
    const float* b1       = (const float*)d_in[3];
    const float* W2       = (const float*)d_in[4];
    const float* b2       = (const float*)d_in[5];
    const int*   src      = (const int*)d_in[6];
    const int*   dst      = (const int*)d_in[7];
    float* out = (float*)d_out;

    // Workspace layout (29.2 MB, known-good). hw aliases xw (xw dead after
    // spmm1; gemm2 launches after it on the same stream).
    const size_t OFF_H    = 12800000;
    const size_t OFF_ROFF = 25600000;
    const size_t OFF_CUR  = 25800016;
    const size_t OFF_PERM = 26000016;
    const size_t REQUIRED = OFF_PERM + (size_t)N_EDGES * 4;  // 29,200,016 B
    if (ws_size < REQUIRED) return;

    char* ws = (char*)d_ws;
    float* xw      = (float*)(ws);
    float* hw      = (float*)(ws);               // alias of xw (see above)
    float* h       = (float*)(ws + OFF_H);
    int*   row_off = (int*)  (ws + OFF_ROFF);
    int*   cursor  = (int*)  (ws + OFF_CUR);
    int*   perm    = (int*)  (ws + OFF_PERM);

    // CSR build (ws is poisoned 0xAA each call -> zero the counters first)
    zero_kernel<<<(N_NODES + 255) / 256, 256, 0, stream>>>(cursor, N_NODES);
    hist_kernel<<<(N_EDGES + 255) / 256, 256, 0, stream>>>(dst, cursor);
    scan_kernel<<<1, 1024, 0, stream>>>(cursor, row_off);
    scatter_kernel<<<(N_EDGES + 255) / 256, 256, 0, stream>>>(dst, cursor, perm);

    // Dense + sparse pipeline
    gemm1_kernel<<<(N_NODES + 63) / 64, 256, 0, stream>>>(x, W1, xw);
    spmm1_kernel<<<(N_NODES + 3) / 4, 256, 0, stream>>>(xw, adj_vals, src, perm, row_off, b1, h);
    gemm2_kernel<<<((N_NODES + 7) / 8 + 3) / 4, 256, 0, stream>>>(h, W2, hw);
    spmm2_lsm_kernel<<<(N_NODES + 3) / 4, 256, 0, stream>>>(hw, adj_vals, src, perm, row_off, b2, out);
}

// Round 7
// 525.761 us; speedup vs baseline: 1.1305x; 1.1305x over previous
//
#include <hip/hip_runtime.h>
#include <math.h>

#define N_NODES 50000
#define N_EDGES 800000
#define NFEAT   512
#define NHID    64
#define NCLASS  40

// ---------------------------------------------------------------------------
// CSR build: histogram of dst -> exclusive scan -> scatter edge PAYLOAD
// (src, val) into dst-sorted arrays, so SpMM reads are sequential + 1 gather.
// ---------------------------------------------------------------------------

__global__ void zero_kernel(int* __restrict__ p, int n) {
    int i = blockIdx.x * blockDim.x + threadIdx.x;
    if (i < n) p[i] = 0;
}

__global__ void hist_kernel(const int* __restrict__ dst, int* __restrict__ counts) {
    int i = blockIdx.x * blockDim.x + threadIdx.x;
    if (i < N_EDGES) atomicAdd(&counts[dst[i]], 1);
}

__global__ __launch_bounds__(1024) void scan_kernel(int* __restrict__ cnt_next,
                                                    int* __restrict__ row_off) {
    __shared__ int lds[1024];
    const int t  = threadIdx.x;
    const int CH = (N_NODES + 1023) / 1024;      // 49
    const int lo = t * CH;
    const int hi = (lo + CH < N_NODES) ? lo + CH : N_NODES;

    int s = 0;
    for (int i = lo; i < hi; ++i) s += cnt_next[i];
    lds[t] = s;
    __syncthreads();
    for (int off = 1; off < 1024; off <<= 1) {
        int v = (t >= off) ? lds[t - off] : 0;
        __syncthreads();
        lds[t] += v;
        __syncthreads();
    }
    int excl  = lds[t] - s;
    int total = lds[1023];

    int run = excl;
    for (int i = lo; i < hi; ++i) {
        int c = cnt_next[i];          // read before overwrite (same buffer)
        row_off[i]  = run;
        cnt_next[i] = run;            // becomes the scatter cursor
        run += c;
    }
    if (t == 0) row_off[N_NODES] = total;
}

__global__ void scatter_kernel(const int* __restrict__ dst,
                               const int* __restrict__ src,
                               const float* __restrict__ adj_vals,
                               int* __restrict__ cursor,
                               int* __restrict__ src_s,
                               float* __restrict__ val_s) {
    int i = blockIdx.x * blockDim.x + threadIdx.x;
    if (i < N_EDGES) {
        int p = atomicAdd(&cursor[dst[i]], 1);
        src_s[p] = src[i];
        val_s[p] = adj_vals[i];
    }
}

// ---------------------------------------------------------------------------
// GEMM1 v3: xw = x @ W1.  [50000,512] x [512,64].
// Block 256 (4 waves), tile 64 rows x 64 cols, lane tile 4x4, acc carried
// across all K. K-chunks of 64. BOTH operands staged through LDS with
// COALESCED global loads (4 float4 each per thread per chunk, independent,
// throughput-bound) -- rounds 5/6 proved broadcast global x-loads are
// latency-bound at 24-30% VALUBusy regardless of prefetch depth.
// Inner loop: x read from LDS via broadcast addrs (4 unique x 16B = cheap),
// W via swizzle slot(k0,c,i16)=k0*64+c*16+i16 (16 consecutive slots/instr,
// conflict-free; staging writes linear = conflict-free, col via inverse
// swizzle). LDS 33.4 KB -> 4 blocks/CU.
// ---------------------------------------------------------------------------
#define G1_BK 64

__global__ __launch_bounds__(256, 4) void gemm1_kernel(const float* __restrict__ x,
                                                       const float* __restrict__ W1,
                                                       float* __restrict__ xw) {
    __shared__ float4 wlds[16 * 64];     // 16 KB: [k0][slot]
    __shared__ float4 xlds[64 * 17];     // 17.4 KB: [row][k0], +1 f4 pad
    const int tid  = threadIdx.x;
    const int lane = tid & 63;
    const int i16  = lane & 15;
    const int rg   = lane >> 4;
    const int wave = tid >> 6;

    const int block_row0 = blockIdx.x * 64;
    int rows[4];
#pragma unroll
    for (int r = 0; r < 4; ++r) rows[r] = block_row0 + wave * 16 + rg * 4 + r;

    float acc[4][4];
#pragma unroll
    for (int r = 0; r < 4; ++r)
#pragma unroll
        for (int c = 0; c < 4; ++c) acc[r][c] = 0.f;

    for (int chunk = 0; chunk < NFEAT / G1_BK; ++chunk) {
        const int kb = chunk * G1_BK;
        __syncthreads();                 // previous chunk's LDS reads done
        // Stage W1[kb..kb+63][0..63]: linear writes, inverse-swizzled col.
        for (int idx = tid; idx < 16 * 64; idx += 256) {
            int k0  = idx >> 6;
            int s   = idx & 63;
            int col = 4 * (s & 15) + (s >> 4);
            float4 v;
            v.x = W1[(kb + 4 * k0 + 0) * NHID + col];
            v.y = W1[(kb + 4 * k0 + 1) * NHID + col];
            v.z = W1[(kb + 4 * k0 + 2) * NHID + col];
            v.w = W1[(kb + 4 * k0 + 3) * NHID + col];
            wlds[idx] = v;
        }
        // Stage x[block_row0..+63][kb..kb+63]: fully coalesced (16 lanes
        // cover one row's 256B contiguously).
        for (int idx = tid; idx < 64 * 16; idx += 256) {
            int row = idx >> 4;
            int c4  = idx & 15;
            int gr  = block_row0 + row;
            if (gr > N_NODES - 1) gr = N_NODES - 1;   // tail clamp (stores guarded)
            xlds[row * 17 + c4] =
                *reinterpret_cast<const float4*>(x + (size_t)gr * NFEAT + kb + 4 * c4);
        }
        __syncthreads();

#pragma unroll
        for (int k0 = 0; k0 < 16; ++k0) {
            float4 wv[4];
#pragma unroll
            for (int c = 0; c < 4; ++c)
                wv[c] = wlds[k0 * 64 + c * 16 + i16];
            float4 xv[4];
#pragma unroll
            for (int r = 0; r < 4; ++r)
                xv[r] = xlds[(wave * 16 + rg * 4 + r) * 17 + k0];
#pragma unroll
            for (int r = 0; r < 4; ++r)
#pragma unroll
                for (int c = 0; c < 4; ++c)
                    acc[r][c] = fmaf(xv[r].x, wv[c].x,
                                fmaf(xv[r].y, wv[c].y,
                                fmaf(xv[r].z, wv[c].z,
                                fmaf(xv[r].w, wv[c].w, acc[r][c]))));
        }
    }

#pragma unroll
    for (int r = 0; r < 4; ++r) {
        if (rows[r] < N_NODES) {
            float4 o; o.x = acc[r][0]; o.y = acc[r][1]; o.z = acc[r][2]; o.w = acc[r][3];
            *reinterpret_cast<float4*>(&xw[(size_t)rows[r] * NHID + 4 * i16]) = o;
        }
    }
}

// ---------------------------------------------------------------------------
// SpMM1 + bias + relu. Wave per row, lane = feature. src_s/val_s are
// dst-sorted: sequential L1-hit reads + ONE gather per edge (was a 3-deep
// chase through perm). Unroll 8 for outstanding-gather depth.
// ---------------------------------------------------------------------------
__global__ void spmm1_kernel(const float* __restrict__ xw,
                             const int* __restrict__ src_s,
                             const float* __restrict__ val_s,
                             const int* __restrict__ row_off,
                             const float* __restrict__ b1,
                             float* __restrict__ h) {
    const int lane = threadIdx.x & 63;
    const int row  = blockIdx.x * 4 + (threadIdx.x >> 6);
    if (row >= N_NODES) return;
    const int lo = row_off[row], hi = row_off[row + 1];
    float acc = 0.f;
    int i = lo;
    for (; i + 7 < hi; i += 8) {
        int   s[8];
        float v[8];
#pragma unroll
        for (int j = 0; j < 8; ++j) { s[j] = src_s[i + j]; v[j] = val_s[i + j]; }
#pragma unroll
        for (int j = 0; j < 8; ++j)
            acc += v[j] * xw[(size_t)s[j] * NHID + lane];
    }
    for (; i < hi; ++i)
        acc += val_s[i] * xw[(size_t)src_s[i] * NHID + lane];
    h[(size_t)row * NHID + lane] = fmaxf(acc + b1[lane], 0.f);
}

// ---------------------------------------------------------------------------
// GEMM2 v2: hw = h @ W2. [50000,64] x [64,40]. Same LDS-tile structure as
// gemm1 v3 (single K-chunk = 64). Lane tile 4x4; col group i16<10 active.
// W2 swizzle slot(k0,c,i16)=k0*40+c*10+i16 -> col 4*i16+c.
// ---------------------------------------------------------------------------
__global__ __launch_bounds__(256) void gemm2_kernel(const float* __restrict__ h,
                                                    const float* __restrict__ W2,
                                                    float* __restrict__ hw) {
    __shared__ float4 w2lds[16 * 40];    // 10 KB
    __shared__ float4 hlds[64 * 17];     // 17.4 KB
    const int tid  = threadIdx.x;
    const int lane = tid & 63;
    const int i16  = lane & 15;
    const int rg   = lane >> 4;
    const int wave = tid >> 6;
    const int i16c = (i16 < 10) ? i16 : 9;    // clamp for LDS reads

    const int block_row0 = blockIdx.x * 64;

    for (int idx = tid; idx < 16 * 40; idx += 256) {
        int k0 = idx / 40, s = idx % 40;
        int c = s / 10, ig = s % 10;
        int col = 4 * ig + c;
        float4 v;
        v.x = W2[(4 * k0 + 0) * NCLASS + col];
        v.y = W2[(4 * k0 + 1) * NCLASS + col];
        v.z = W2[(4 * k0 + 2) * NCLASS + col];
        v.w = W2[(4 * k0 + 3) * NCLASS + col];
        w2lds[idx] = v;
    }
    for (int idx = tid; idx < 64 * 16; idx += 256) {
        int row = idx >> 4;
        int c4  = idx & 15;
        int gr  = block_row0 + row;
        if (gr > N_NODES - 1) gr = N_NODES - 1;
        hlds[row * 17 + c4] =
            *reinterpret_cast<const float4*>(h + (size_t)gr * NHID + 4 * c4);
    }
    __syncthreads();

    float acc[4][4];
#pragma unroll
    for (int r = 0; r < 4; ++r)
#pragma unroll
        for (int c = 0; c < 4; ++c) acc[r][c] = 0.f;

#pragma unroll
    for (int k0 = 0; k0 < 16; ++k0) {
        float4 wv[4];
#pragma unroll
        for (int c = 0; c < 4; ++c)
            wv[c] = w2lds[k0 * 40 + c * 10 + i16c];
        float4 xv[4];
#pragma unroll
        for (int r = 0; r < 4; ++r)
            xv[r] = hlds[(wave * 16 + rg * 4 + r) * 17 + k0];
#pragma unroll
        for (int r = 0; r < 4; ++r)
#pragma unroll
            for (int c = 0; c < 4; ++c)
                acc[r][c] = fmaf(xv[r].x, wv[c].x,
                            fmaf(xv[r].y, wv[c].y,
                            fmaf(xv[r].z, wv[c].z,
                            fmaf(xv[r].w, wv[c].w, acc[r][c]))));
    }

#pragma unroll
    for (int r = 0; r < 4; ++r) {
        int row = block_row0 + wave * 16 + rg * 4 + r;
        if (i16 < 10 && row < N_NODES) {
            float4 o; o.x = acc[r][0]; o.y = acc[r][1]; o.z = acc[r][2]; o.w = acc[r][3];
            *reinterpret_cast<float4*>(&hw[(size_t)row * NCLASS + 4 * i16]) = o;
        }
    }
}

// ---------------------------------------------------------------------------
// SpMM2 + b2 + log_softmax. Wave per row, lanes 0..39 = classes.
// ---------------------------------------------------------------------------
__global__ void spmm2_lsm_kernel(const float* __restrict__ hw,
                                 const int* __restrict__ src_s,
                                 const float* __restrict__ val_s,
                                 const int* __restrict__ row_off,
                                 const float* __restrict__ b2,
                                 float* __restrict__ out) {
    const int lane = threadIdx.x & 63;
    const int row  = blockIdx.x * 4 + (threadIdx.x >> 6);
    if (row >= N_NODES) return;
    const bool active = lane < NCLASS;
    const int cl = active ? lane : (NCLASS - 1);
    const int lo = row_off[row], hi = row_off[row + 1];
    float acc = 0.f;
    int i = lo;
    for (; i + 7 < hi; i += 8) {
        int   s[8];
        float v[8];
#pragma unroll
        for (int j = 0; j < 8; ++j) { s[j] = src_s[i + j]; v[j] = val_s[i + j]; }
#pragma unroll
        for (int j = 0; j < 8; ++j)
            acc += v[j] * hw[(size_t)s[j] * NCLASS + cl];
    }
    for (; i < hi; ++i)
        acc += val_s[i] * hw[(size_t)src_s[i] * NCLASS + cl];

    float logit = acc + b2[cl];
    float m = active ? logit : -INFINITY;
#pragma unroll
    for (int o = 32; o > 0; o >>= 1) m = fmaxf(m, __shfl_xor(m, o));
    float ex = active ? expf(logit - m) : 0.f;
    float ssum = ex;
#pragma unroll
    for (int o = 32; o > 0; o >>= 1) ssum += __shfl_xor(ssum, o);
    if (active) out[(size_t)row * NCLASS + lane] = logit - m - logf(ssum);
}

// ---------------------------------------------------------------------------

extern "C" void kernel_launch(void* const* d_in, const int* in_sizes, int n_in,
                              void* d_out, int out_size, void* d_ws, size_t ws_size,
                              hipStream_t stream) {
    const float* x        = (const float*)d_in[0];
    const float* adj_vals = (const float*)d_in[1];
    const float* W1       = (const float*)d_in[2];
    const float* b1       = (const float*)d_in[3];
    const float* W2       = (const float*)d_in[4];
    const float* b2       = (const float*)d_in[5];
    const int*   src      = (const int*)d_in[6];
    const int*   dst      = (const int*)d_in[7];
    float* out = (float*)d_out;

    // Workspace layout (32.4 MB). hw aliases xw (xw dead after spmm1;
    // gemm2 writes hw afterwards on the same stream).
    const size_t OFF_H    = 12800000;            // h     : 50000*64 f32
    const size_t OFF_ROFF = 25600000;            // row_off: 50001 int
    const size_t OFF_CUR  = 25800016;            // cursor : 50000 int
    const size_t OFF_SRC  = 26000016;            // src_s  : 800000 int
    const size_t OFF_VAL  = 29200016;            // val_s  : 800000 f32
    const size_t REQUIRED = OFF_VAL + (size_t)N_EDGES * 4;   // 32,400,016 B
    if (ws_size < REQUIRED) return;              // refuse to write OOB

    char* ws = (char*)d_ws;
    float* xw      = (float*)(ws);
    float* hw      = (float*)(ws);               // alias (see above)
    float* h       = (float*)(ws + OFF_H);
    int*   row_off = (int*)  (ws + OFF_ROFF);
    int*   cursor  = (int*)  (ws + OFF_CUR);
    int*   src_s   = (int*)  (ws + OFF_SRC);
    float* val_s   = (float*)(ws + OFF_VAL);

    // CSR build (ws is poisoned 0xAA each call -> zero the counters first)
    zero_kernel<<<(N_NODES + 255) / 256, 256, 0, stream>>>(cursor, N_NODES);
    hist_kernel<<<(N_EDGES + 255) / 256, 256, 0, stream>>>(dst, cursor);
    scan_kernel<<<1, 1024, 0, stream>>>(cursor, row_off);
    scatter_kernel<<<(N_EDGES + 255) / 256, 256, 0, stream>>>(dst, src, adj_vals,
                                                              cursor, src_s, val_s);

    // Dense + sparse pipeline
    gemm1_kernel<<<(N_NODES + 63) / 64, 256, 0, stream>>>(x, W1, xw);
    spmm1_kernel<<<(N_NODES + 3) / 4, 256, 0, stream>>>(xw, src_s, val_s, row_off, b1, h);
    gemm2_kernel<<<(N_NODES + 63) / 64, 256, 0, stream>>>(h, W2, hw);
    spmm2_lsm_kernel<<<(N_NODES + 3) / 4, 256, 0, stream>>>(hw, src_s, val_s, row_off, b2, out);
}

// Round 8
// 428.745 us; speedup vs baseline: 1.3863x; 1.2263x over previous
//
#include <hip/hip_runtime.h>
#include <math.h>

#define N_NODES 50000
#define N_EDGES 800000
#define NFEAT   512
#define NHID    64
#define NCLASS  40

// ---------------------------------------------------------------------------
// CSR build: histogram of dst -> 3-phase multi-block exclusive scan ->
// scatter edge payload (src, val) into dst-sorted arrays.
// Round 7 showed the single-block scan was the #1 dispatch (112 us,
// occupancy 0.14%, VALUBusy 0.01 -- serial latency-bound). 3-phase scan
// parallelizes it across 98 blocks.
// ---------------------------------------------------------------------------

#define STILE  512
#define NTILES ((N_NODES + STILE - 1) / STILE)   // 98

__global__ void zero_kernel(int* __restrict__ p, int n) {
    int i = blockIdx.x * blockDim.x + threadIdx.x;
    if (i < n) p[i] = 0;
}

__global__ void hist_kernel(const int* __restrict__ dst, int* __restrict__ counts) {
    int i = blockIdx.x * blockDim.x + threadIdx.x;
    if (i < N_EDGES) atomicAdd(&counts[dst[i]], 1);
}

// Phase 1: per-tile sums (coalesced reads, shfl + LDS reduction).
__global__ __launch_bounds__(STILE) void tile_sum_kernel(const int* __restrict__ counts,
                                                         int* __restrict__ tile_sums) {
    __shared__ int wsum[STILE / 64];
    const int t = threadIdx.x, b = blockIdx.x;
    const int i = b * STILE + t;
    int v = (i < N_NODES) ? counts[i] : 0;
#pragma unroll
    for (int o = 32; o > 0; o >>= 1) v += __shfl_down(v, o);
    if ((t & 63) == 0) wsum[t >> 6] = v;
    __syncthreads();
    if (t < STILE / 64) {
        int s = wsum[t];
#pragma unroll
        for (int o = STILE / 128; o > 0; o >>= 1) s += __shfl_down(s, o);
        if (t == 0) tile_sums[b] = s;
    }
}

// Phase 2: exclusive scan of the 98 tile sums (one tiny block); also emits
// the grand total into row_off[N_NODES].
__global__ __launch_bounds__(128) void tile_scan_kernel(const int* __restrict__ tile_sums,
                                                        int* __restrict__ tile_off,
                                                        int* __restrict__ row_off) {
    __shared__ int lds[128];
    const int t = threadIdx.x;
    int v = (t < NTILES) ? tile_sums[t] : 0;
    lds[t] = v;
    __syncthreads();
    for (int off = 1; off < 128; off <<= 1) {
        int u = (t >= off) ? lds[t - off] : 0;
        __syncthreads();
        lds[t] += u;
        __syncthreads();
    }
    if (t < NTILES) tile_off[t] = lds[t] - v;
    if (t == 127) row_off[N_NODES] = lds[127];
}

// Phase 3: intra-tile exclusive scan + tile offset -> row_off and cursor.
// cursor aliases counts (each thread touches only its own index: safe).
__global__ __launch_bounds__(STILE) void tile_apply_kernel(const int* __restrict__ counts,
                                                           const int* __restrict__ tile_off,
                                                           int* __restrict__ row_off,
                                                           int* __restrict__ cursor) {
    __shared__ int lds[STILE];
    const int t = threadIdx.x, b = blockIdx.x;
    const int i = b * STILE + t;
    int v = (i < N_NODES) ? counts[i] : 0;
    lds[t] = v;
    __syncthreads();
    for (int off = 1; off < STILE; off <<= 1) {
        int u = (t >= off) ? lds[t - off] : 0;
        __syncthreads();
        lds[t] += u;
        __syncthreads();
    }
    if (i < N_NODES) {
        int excl = tile_off[b] + lds[t] - v;
        row_off[i] = excl;
        cursor[i]  = excl;
    }
}

__global__ void scatter_kernel(const int* __restrict__ dst,
                               const int* __restrict__ src,
                               const float* __restrict__ adj_vals,
                               int* __restrict__ cursor,
                               int* __restrict__ src_s,
                               float* __restrict__ val_s) {
    int i = blockIdx.x * blockDim.x + threadIdx.x;
    if (i < N_EDGES) {
        int p = atomicAdd(&cursor[dst[i]], 1);
        src_s[p] = src[i];
        val_s[p] = adj_vals[i];
    }
}

// ---------------------------------------------------------------------------
// GEMM1 v3: xw = x @ W1.  [50000,512] x [512,64].
// Block 256 (4 waves), tile 64x64, lane tile 4x4, acc carried across K.
// Both operands staged through LDS with coalesced loads (rounds 5/6 proved
// broadcast global x-loads are latency-bound at 24-30% VALUBusy).
// ---------------------------------------------------------------------------
#define G1_BK 64

__global__ __launch_bounds__(256, 4) void gemm1_kernel(const float* __restrict__ x,
                                                       const float* __restrict__ W1,
                                                       float* __restrict__ xw) {
    __shared__ float4 wlds[16 * 64];     // 16 KB: [k0][slot]
    __shared__ float4 xlds[64 * 17];     // 17.4 KB: [row][k0], +1 f4 pad
    const int tid  = threadIdx.x;
    const int lane = tid & 63;
    const int i16  = lane & 15;
    const int rg   = lane >> 4;
    const int wave = tid >> 6;

    const int block_row0 = blockIdx.x * 64;
    int rows[4];
#pragma unroll
    for (int r = 0; r < 4; ++r) rows[r] = block_row0 + wave * 16 + rg * 4 + r;

    float acc[4][4];
#pragma unroll
    for (int r = 0; r < 4; ++r)
#pragma unroll
        for (int c = 0; c < 4; ++c) acc[r][c] = 0.f;

    for (int chunk = 0; chunk < NFEAT / G1_BK; ++chunk) {
        const int kb = chunk * G1_BK;
        __syncthreads();
        for (int idx = tid; idx < 16 * 64; idx += 256) {
            int k0  = idx >> 6;
            int s   = idx & 63;
            int col = 4 * (s & 15) + (s >> 4);
            float4 v;
            v.x = W1[(kb + 4 * k0 + 0) * NHID + col];
            v.y = W1[(kb + 4 * k0 + 1) * NHID + col];
            v.z = W1[(kb + 4 * k0 + 2) * NHID + col];
            v.w = W1[(kb + 4 * k0 + 3) * NHID + col];
            wlds[idx] = v;
        }
        for (int idx = tid; idx < 64 * 16; idx += 256) {
            int row = idx >> 4;
            int c4  = idx & 15;
            int gr  = block_row0 + row;
            if (gr > N_NODES - 1) gr = N_NODES - 1;
            xlds[row * 17 + c4] =
                *reinterpret_cast<const float4*>(x + (size_t)gr * NFEAT + kb + 4 * c4);
        }
        __syncthreads();

#pragma unroll
        for (int k0 = 0; k0 < 16; ++k0) {
            float4 wv[4];
#pragma unroll
            for (int c = 0; c < 4; ++c)
                wv[c] = wlds[k0 * 64 + c * 16 + i16];
            float4 xv[4];
#pragma unroll
            for (int r = 0; r < 4; ++r)
                xv[r] = xlds[(wave * 16 + rg * 4 + r) * 17 + k0];
#pragma unroll
            for (int r = 0; r < 4; ++r)
#pragma unroll
                for (int c = 0; c < 4; ++c)
                    acc[r][c] = fmaf(xv[r].x, wv[c].x,
                                fmaf(xv[r].y, wv[c].y,
                                fmaf(xv[r].z, wv[c].z,
                                fmaf(xv[r].w, wv[c].w, acc[r][c]))));
        }
    }

#pragma unroll
    for (int r = 0; r < 4; ++r) {
        if (rows[r] < N_NODES) {
            float4 o; o.x = acc[r][0]; o.y = acc[r][1]; o.z = acc[r][2]; o.w = acc[r][3];
            *reinterpret_cast<float4*>(&xw[(size_t)rows[r] * NHID + 4 * i16]) = o;
        }
    }
}

// ---------------------------------------------------------------------------
// SpMM1 + bias + relu. Wave per row, lane = feature. Sequential src_s/val_s
// reads + one gather per edge; unroll 8 for outstanding-gather depth.
// ---------------------------------------------------------------------------
__global__ void spmm1_kernel(const float* __restrict__ xw,
                             const int* __restrict__ src_s,
                             const float* __restrict__ val_s,
                             const int* __restrict__ row_off,
                             const float* __restrict__ b1,
                             float* __restrict__ h) {
    const int lane = threadIdx.x & 63;
    const int row  = blockIdx.x * 4 + (threadIdx.x >> 6);
    if (row >= N_NODES) return;
    const int lo = row_off[row], hi = row_off[row + 1];
    float acc = 0.f;
    int i = lo;
    for (; i + 7 < hi; i += 8) {
        int   s[8];
        float v[8];
#pragma unroll
        for (int j = 0; j < 8; ++j) { s[j] = src_s[i + j]; v[j] = val_s[i + j]; }
#pragma unroll
        for (int j = 0; j < 8; ++j)
            acc += v[j] * xw[(size_t)s[j] * NHID + lane];
    }
    for (; i < hi; ++i)
        acc += val_s[i] * xw[(size_t)src_s[i] * NHID + lane];
    h[(size_t)row * NHID + lane] = fmaxf(acc + b1[lane], 0.f);
}

// ---------------------------------------------------------------------------
// GEMM2 v2: hw = h @ W2. [50000,64] x [64,40]. LDS-tiled like gemm1 v3.
// ---------------------------------------------------------------------------
__global__ __launch_bounds__(256) void gemm2_kernel(const float* __restrict__ h,
                                                    const float* __restrict__ W2,
                                                    float* __restrict__ hw) {
    __shared__ float4 w2lds[16 * 40];    // 10 KB
    __shared__ float4 hlds[64 * 17];     // 17.4 KB
    const int tid  = threadIdx.x;
    const int lane = tid & 63;
    const int i16  = lane & 15;
    const int rg   = lane >> 4;
    const int wave = tid >> 6;
    const int i16c = (i16 < 10) ? i16 : 9;

    const int block_row0 = blockIdx.x * 64;

    for (int idx = tid; idx < 16 * 40; idx += 256) {
        int k0 = idx / 40, s = idx % 40;
        int c = s / 10, ig = s % 10;
        int col = 4 * ig + c;
        float4 v;
        v.x = W2[(4 * k0 + 0) * NCLASS + col];
        v.y = W2[(4 * k0 + 1) * NCLASS + col];
        v.z = W2[(4 * k0 + 2) * NCLASS + col];
        v.w = W2[(4 * k0 + 3) * NCLASS + col];
        w2lds[idx] = v;
    }
    for (int idx = tid; idx < 64 * 16; idx += 256) {
        int row = idx >> 4;
        int c4  = idx & 15;
        int gr  = block_row0 + row;
        if (gr > N_NODES - 1) gr = N_NODES - 1;
        hlds[row * 17 + c4] =
            *reinterpret_cast<const float4*>(h + (size_t)gr * NHID + 4 * c4);
    }
    __syncthreads();

    float acc[4][4];
#pragma unroll
    for (int r = 0; r < 4; ++r)
#pragma unroll
        for (int c = 0; c < 4; ++c) acc[r][c] = 0.f;

#pragma unroll
    for (int k0 = 0; k0 < 16; ++k0) {
        float4 wv[4];
#pragma unroll
        for (int c = 0; c < 4; ++c)
            wv[c] = w2lds[k0 * 40 + c * 10 + i16c];
        float4 xv[4];
#pragma unroll
        for (int r = 0; r < 4; ++r)
            xv[r] = hlds[(wave * 16 + rg * 4 + r) * 17 + k0];
#pragma unroll
        for (int r = 0; r < 4; ++r)
#pragma unroll
            for (int c = 0; c < 4; ++c)
                acc[r][c] = fmaf(xv[r].x, wv[c].x,
                            fmaf(xv[r].y, wv[c].y,
                            fmaf(xv[r].z, wv[c].z,
                            fmaf(xv[r].w, wv[c].w, acc[r][c]))));
    }

#pragma unroll
    for (int r = 0; r < 4; ++r) {
        int row = block_row0 + wave * 16 + rg * 4 + r;
        if (i16 < 10 && row < N_NODES) {
            float4 o; o.x = acc[r][0]; o.y = acc[r][1]; o.z = acc[r][2]; o.w = acc[r][3];
            *reinterpret_cast<float4*>(&hw[(size_t)row * NCLASS + 4 * i16]) = o;
        }
    }
}

// ---------------------------------------------------------------------------
// SpMM2 + b2 + log_softmax. Wave per row, lanes 0..39 = classes.
// ---------------------------------------------------------------------------
__global__ void spmm2_lsm_kernel(const float* __restrict__ hw,
                                 const int* __restrict__ src_s,
                                 const float* __restrict__ val_s,
                                 const int* __restrict__ row_off,
                                 const float* __restrict__ b2,
                                 float* __restrict__ out) {
    const int lane = threadIdx.x & 63;
    const int row  = blockIdx.x * 4 + (threadIdx.x >> 6);
    if (row >= N_NODES) return;
    const bool active = lane < NCLASS;
    const int cl = active ? lane : (NCLASS - 1);
    const int lo = row_off[row], hi = row_off[row + 1];
    float acc = 0.f;
    int i = lo;
    for (; i + 7 < hi; i += 8) {
        int   s[8];
        float v[8];
#pragma unroll
        for (int j = 0; j < 8; ++j) { s[j] = src_s[i + j]; v[j] = val_s[i + j]; }
#pragma unroll
        for (int j = 0; j < 8; ++j)
            acc += v[j] * hw[(size_t)s[j] * NCLASS + cl];
    }
    for (; i < hi; ++i)
        acc += val_s[i] * hw[(size_t)src_s[i] * NCLASS + cl];

    float logit = acc + b2[cl];
    float m = active ? logit : -INFINITY;
#pragma unroll
    for (int o = 32; o > 0; o >>= 1) m = fmaxf(m, __shfl_xor(m, o));
    float ex = active ? expf(logit - m) : 0.f;
    float ssum = ex;
#pragma unroll
    for (int o = 32; o > 0; o >>= 1) ssum += __shfl_xor(ssum, o);
    if (active) out[(size_t)row * NCLASS + lane] = logit - m - logf(ssum);
}

// ---------------------------------------------------------------------------

extern "C" void kernel_launch(void* const* d_in, const int* in_sizes, int n_in,
                              void* d_out, int out_size, void* d_ws, size_t ws_size,
                              hipStream_t stream) {
    const float* x        = (const float*)d_in[0];
    const float* adj_vals = (const float*)d_in[1];
    const float* W1       = (const float*)d_in[2];
    const float* b1       = (const float*)d_in[3];
    const float* W2       = (const float*)d_in[4];
    const float* b2       = (const float*)d_in[5];
    const int*   src      = (const int*)d_in[6];
    const int*   dst      = (const int*)d_in[7];
    float* out = (float*)d_out;

    // Workspace layout (32.4 MB + scan temporaries). hw aliases xw.
    const size_t OFF_H    = 12800000;            // h     : 50000*64 f32
    const size_t OFF_ROFF = 25600000;            // row_off: 50001 int
    const size_t OFF_CUR  = 25800016;            // cursor : 50000 int (aliases counts)
    const size_t OFF_SRC  = 26000016;            // src_s  : 800000 int
    const size_t OFF_VAL  = 29200016;            // val_s  : 800000 f32
    const size_t OFF_TS   = 32400016;            // tile_sums: NTILES int
    const size_t OFF_TO   = OFF_TS + NTILES * 4; // tile_off : NTILES int
    const size_t REQUIRED = OFF_TO + NTILES * 4; // 32,400,800 B
    if (ws_size < REQUIRED) return;              // refuse to write OOB

    char* ws = (char*)d_ws;
    float* xw        = (float*)(ws);
    float* hw        = (float*)(ws);             // alias (xw dead after spmm1)
    float* h         = (float*)(ws + OFF_H);
    int*   row_off   = (int*)  (ws + OFF_ROFF);
    int*   counts    = (int*)  (ws + OFF_CUR);   // histogram, then cursor
    int*   src_s     = (int*)  (ws + OFF_SRC);
    float* val_s     = (float*)(ws + OFF_VAL);
    int*   tile_sums = (int*)  (ws + OFF_TS);
    int*   tile_off  = (int*)  (ws + OFF_TO);

    // CSR build (ws poisoned 0xAA each call -> zero the counters first)
    zero_kernel<<<(N_NODES + 255) / 256, 256, 0, stream>>>(counts, N_NODES);
    hist_kernel<<<(N_EDGES + 255) / 256, 256, 0, stream>>>(dst, counts);
    tile_sum_kernel<<<NTILES, STILE, 0, stream>>>(counts, tile_sums);
    tile_scan_kernel<<<1, 128, 0, stream>>>(tile_sums, tile_off, row_off);
    tile_apply_kernel<<<NTILES, STILE, 0, stream>>>(counts, tile_off, row_off, counts);
    scatter_kernel<<<(N_EDGES + 255) / 256, 256, 0, stream>>>(dst, src, adj_vals,
                                                              counts, src_s, val_s);

    // Dense + sparse pipeline
    gemm1_kernel<<<(N_NODES + 63) / 64, 256, 0, stream>>>(x, W1, xw);
    spmm1_kernel<<<(N_NODES + 3) / 4, 256, 0, stream>>>(xw, src_s, val_s, row_off, b1, h);
    gemm2_kernel<<<(N_NODES + 63) / 64, 256, 0, stream>>>(h, W2, hw);
    spmm2_lsm_kernel<<<(N_NODES + 3) / 4, 256, 0, stream>>>(hw, src_s, val_s, row_off, b2, out);
}

// Round 9
// 388.185 us; speedup vs baseline: 1.5311x; 1.1045x over previous
//
#include <hip/hip_runtime.h>
#include <math.h>

#define N_NODES 50000
#define N_EDGES 800000
#define NFEAT   512
#define NHID    64
#define NCLASS  40

typedef __attribute__((ext_vector_type(8))) short bf16x8;   // 8 bf16 (4 VGPRs)
typedef __attribute__((ext_vector_type(4))) float f32x4;    // MFMA C/D

__device__ inline unsigned short f2bf(float f) {            // fp32 -> bf16 RNE
    unsigned int u = __float_as_uint(f);
    u += 0x7FFFu + ((u >> 16) & 1u);
    return (unsigned short)(u >> 16);
}

// ---------------------------------------------------------------------------
// CSR build: histogram of dst -> 3-phase multi-block exclusive scan ->
// scatter edge payload (src, val) into dst-sorted arrays.
// ---------------------------------------------------------------------------

#define STILE  512
#define NTILES ((N_NODES + STILE - 1) / STILE)   // 98

__global__ void zero_kernel(int* __restrict__ p, int n) {
    int i = blockIdx.x * blockDim.x + threadIdx.x;
    if (i < n) p[i] = 0;
}

__global__ void hist_kernel(const int* __restrict__ dst, int* __restrict__ counts) {
    int i = blockIdx.x * blockDim.x + threadIdx.x;
    if (i < N_EDGES) atomicAdd(&counts[dst[i]], 1);
}

__global__ __launch_bounds__(STILE) void tile_sum_kernel(const int* __restrict__ counts,
                                                         int* __restrict__ tile_sums) {
    __shared__ int wsum[STILE / 64];
    const int t = threadIdx.x, b = blockIdx.x;
    const int i = b * STILE + t;
    int v = (i < N_NODES) ? counts[i] : 0;
#pragma unroll
    for (int o = 32; o > 0; o >>= 1) v += __shfl_down(v, o);
    if ((t & 63) == 0) wsum[t >> 6] = v;
    __syncthreads();
    if (t < STILE / 64) {
        int s = wsum[t];
#pragma unroll
        for (int o = STILE / 128; o > 0; o >>= 1) s += __shfl_down(s, o);
        if (t == 0) tile_sums[b] = s;
    }
}

__global__ __launch_bounds__(128) void tile_scan_kernel(const int* __restrict__ tile_sums,
                                                        int* __restrict__ tile_off,
                                                        int* __restrict__ row_off) {
    __shared__ int lds[128];
    const int t = threadIdx.x;
    int v = (t < NTILES) ? tile_sums[t] : 0;
    lds[t] = v;
    __syncthreads();
    for (int off = 1; off < 128; off <<= 1) {
        int u = (t >= off) ? lds[t - off] : 0;
        __syncthreads();
        lds[t] += u;
        __syncthreads();
    }
    if (t < NTILES) tile_off[t] = lds[t] - v;
    if (t == 127) row_off[N_NODES] = lds[127];
}

__global__ __launch_bounds__(STILE) void tile_apply_kernel(const int* __restrict__ counts,
                                                           const int* __restrict__ tile_off,
                                                           int* __restrict__ row_off,
                                                           int* __restrict__ cursor) {
    __shared__ int lds[STILE];
    const int t = threadIdx.x, b = blockIdx.x;
    const int i = b * STILE + t;
    int v = (i < N_NODES) ? counts[i] : 0;
    lds[t] = v;
    __syncthreads();
    for (int off = 1; off < STILE; off <<= 1) {
        int u = (t >= off) ? lds[t - off] : 0;
        __syncthreads();
        lds[t] += u;
        __syncthreads();
    }
    if (i < N_NODES) {
        int excl = tile_off[b] + lds[t] - v;
        row_off[i] = excl;
        cursor[i]  = excl;
    }
}

__global__ void scatter_kernel(const int* __restrict__ dst,
                               const int* __restrict__ src,
                               const float* __restrict__ adj_vals,
                               int* __restrict__ cursor,
                               int* __restrict__ src_s,
                               float* __restrict__ val_s) {
    int i = blockIdx.x * blockDim.x + threadIdx.x;
    if (i < N_EDGES) {
        int p = atomicAdd(&cursor[dst[i]], 1);
        src_s[p] = src[i];
        val_s[p] = adj_vals[i];
    }
}

// ---------------------------------------------------------------------------
// W1 -> bf16, transposed: w1t[col][k] (64 x 512). Tiny pre-pass so gemm1's
// B-fragment loads are 16B-contiguous in k.
// ---------------------------------------------------------------------------
__global__ void w1_bf16t_kernel(const float* __restrict__ W1,
                                unsigned short* __restrict__ w1t) {
    int idx = blockIdx.x * blockDim.x + threadIdx.x;
    if (idx < NFEAT * NHID) {
        int k = idx >> 6, c = idx & 63;          // W1 is [k][c], c fastest
        w1t[(size_t)c * NFEAT + k] = f2bf(W1[idx]);
    }
}

// ---------------------------------------------------------------------------
// GEMM1 v4 (MFMA, LDS-free): xw = x @ W1. [50000,512]x[512,64], bf16 inputs,
// fp32 accumulate. Round 8 showed the fp32 path is LDS-BW-bound (2 B/MAC ->
// 47 us floor; measured 100 us at 35% VALUBusy). MFMA reads fragments from
// registers: per K32-step each lane does 2 coalesced float4 x-loads (+cvt),
// 4 x 16B w1t loads (L1-resident), 4 MFMAs. No LDS, no barriers; x read
// exactly once (102 MB -> HBM-bound ~20 us).
// Fragment maps (HW-verified m89/m120): A[m=lane&15][k=quad*8+j],
// B[k=quad*8+j][n=lane&15], D: col=lane&15, row=quad*4+reg.
// Block 256 = 4 waves; wave w -> rows w*16..+15; cols 0..63 = 4 col-tiles.
// ---------------------------------------------------------------------------
__global__ __launch_bounds__(256) void gemm1_kernel(const float* __restrict__ x,
                                                    const unsigned short* __restrict__ w1t,
                                                    float* __restrict__ xw) {
    const int tid  = threadIdx.x;
    const int lane = tid & 63;
    const int wave = tid >> 6;
    const int i16  = lane & 15;
    const int quad = lane >> 4;

    const int arow = blockIdx.x * 64 + wave * 16 + i16;      // A-frag row
    const int arc  = arow < N_NODES ? arow : N_NODES - 1;
    const float* xrow = x + (size_t)arc * NFEAT + quad * 8;  // lane's k base

    // B-frag base: w1t[col*NFEAT + k], col = ct*16 + i16, k = k0 + quad*8 + j
    const unsigned short* wbase = w1t + (size_t)i16 * NFEAT + quad * 8;

    f32x4 acc[4];
#pragma unroll
    for (int ct = 0; ct < 4; ++ct) acc[ct] = (f32x4){0.f, 0.f, 0.f, 0.f};

#pragma unroll 2
    for (int k0 = 0; k0 < NFEAT; k0 += 32) {
        float4 xa = *reinterpret_cast<const float4*>(xrow + k0);
        float4 xb = *reinterpret_cast<const float4*>(xrow + k0 + 4);
        bf16x8 a;
        a[0] = (short)f2bf(xa.x); a[1] = (short)f2bf(xa.y);
        a[2] = (short)f2bf(xa.z); a[3] = (short)f2bf(xa.w);
        a[4] = (short)f2bf(xb.x); a[5] = (short)f2bf(xb.y);
        a[6] = (short)f2bf(xb.z); a[7] = (short)f2bf(xb.w);
#pragma unroll
        for (int ct = 0; ct < 4; ++ct) {
            bf16x8 b = *reinterpret_cast<const bf16x8*>(wbase + (size_t)ct * 16 * NFEAT + k0);
            acc[ct] = __builtin_amdgcn_mfma_f32_16x16x32_bf16(a, b, acc[ct], 0, 0, 0);
        }
    }

    // Epilogue: D row = wave*16 + quad*4 + reg, col = ct*16 + i16.
    const int orow0 = blockIdx.x * 64 + wave * 16 + quad * 4;
#pragma unroll
    for (int reg = 0; reg < 4; ++reg) {
        int orow = orow0 + reg;
        if (orow < N_NODES) {
            float* op = xw + (size_t)orow * NHID + i16;
#pragma unroll
            for (int ct = 0; ct < 4; ++ct) op[ct * 16] = acc[ct][reg];
        }
    }
}

// ---------------------------------------------------------------------------
// SpMM1 + bias + relu. Wave per row, lane = feature. Sequential src_s/val_s
// reads + one gather per edge; unroll 8 for outstanding-gather depth.
// ---------------------------------------------------------------------------
__global__ void spmm1_kernel(const float* __restrict__ xw,
                             const int* __restrict__ src_s,
                             const float* __restrict__ val_s,
                             const int* __restrict__ row_off,
                             const float* __restrict__ b1,
                             float* __restrict__ h) {
    const int lane = threadIdx.x & 63;
    const int row  = blockIdx.x * 4 + (threadIdx.x >> 6);
    if (row >= N_NODES) return;
    const int lo = row_off[row], hi = row_off[row + 1];
    float acc = 0.f;
    int i = lo;
    for (; i + 7 < hi; i += 8) {
        int   s[8];
        float v[8];
#pragma unroll
        for (int j = 0; j < 8; ++j) { s[j] = src_s[i + j]; v[j] = val_s[i + j]; }
#pragma unroll
        for (int j = 0; j < 8; ++j)
            acc += v[j] * xw[(size_t)s[j] * NHID + lane];
    }
    for (; i < hi; ++i)
        acc += val_s[i] * xw[(size_t)src_s[i] * NHID + lane];
    h[(size_t)row * NHID + lane] = fmaxf(acc + b1[lane], 0.f);
}

// ---------------------------------------------------------------------------
// GEMM2 v2: hw = h @ W2. [50000,64] x [64,40]. LDS-tiled.
// ---------------------------------------------------------------------------
__global__ __launch_bounds__(256) void gemm2_kernel(const float* __restrict__ h,
                                                    const float* __restrict__ W2,
                                                    float* __restrict__ hw) {
    __shared__ float4 w2lds[16 * 40];    // 10 KB
    __shared__ float4 hlds[64 * 17];     // 17.4 KB
    const int tid  = threadIdx.x;
    const int lane = tid & 63;
    const int i16  = lane & 15;
    const int rg   = lane >> 4;
    const int wave = tid >> 6;
    const int i16c = (i16 < 10) ? i16 : 9;

    const int block_row0 = blockIdx.x * 64;

    for (int idx = tid; idx < 16 * 40; idx += 256) {
        int k0 = idx / 40, s = idx % 40;
        int c = s / 10, ig = s % 10;
        int col = 4 * ig + c;
        float4 v;
        v.x = W2[(4 * k0 + 0) * NCLASS + col];
        v.y = W2[(4 * k0 + 1) * NCLASS + col];
        v.z = W2[(4 * k0 + 2) * NCLASS + col];
        v.w = W2[(4 * k0 + 3) * NCLASS + col];
        w2lds[idx] = v;
    }
    for (int idx = tid; idx < 64 * 16; idx += 256) {
        int row = idx >> 4;
        int c4  = idx & 15;
        int gr  = block_row0 + row;
        if (gr > N_NODES - 1) gr = N_NODES - 1;
        hlds[row * 17 + c4] =
            *reinterpret_cast<const float4*>(h + (size_t)gr * NHID + 4 * c4);
    }
    __syncthreads();

    float acc[4][4];
#pragma unroll
    for (int r = 0; r < 4; ++r)
#pragma unroll
        for (int c = 0; c < 4; ++c) acc[r][c] = 0.f;

#pragma unroll
    for (int k0 = 0; k0 < 16; ++k0) {
        float4 wv[4];
#pragma unroll
        for (int c = 0; c < 4; ++c)
            wv[c] = w2lds[k0 * 40 + c * 10 + i16c];
        float4 xv[4];
#pragma unroll
        for (int r = 0; r < 4; ++r)
            xv[r] = hlds[(wave * 16 + rg * 4 + r) * 17 + k0];
#pragma unroll
        for (int r = 0; r < 4; ++r)
#pragma unroll
            for (int c = 0; c < 4; ++c)
                acc[r][c] = fmaf(xv[r].x, wv[c].x,
                            fmaf(xv[r].y, wv[c].y,
                            fmaf(xv[r].z, wv[c].z,
                            fmaf(xv[r].w, wv[c].w, acc[r][c]))));
    }

#pragma unroll
    for (int r = 0; r < 4; ++r) {
        int row = block_row0 + wave * 16 + rg * 4 + r;
        if (i16 < 10 && row < N_NODES) {
            float4 o; o.x = acc[r][0]; o.y = acc[r][1]; o.z = acc[r][2]; o.w = acc[r][3];
            *reinterpret_cast<float4*>(&hw[(size_t)row * NCLASS + 4 * i16]) = o;
        }
    }
}

// ---------------------------------------------------------------------------
// SpMM2 + b2 + log_softmax. Wave per row, lanes 0..39 = classes.
// ---------------------------------------------------------------------------
__global__ void spmm2_lsm_kernel(const float* __restrict__ hw,
                                 const int* __restrict__ src_s,
                                 const float* __restrict__ val_s,
                                 const int* __restrict__ row_off,
                                 const float* __restrict__ b2,
                                 float* __restrict__ out) {
    const int lane = threadIdx.x & 63;
    const int row  = blockIdx.x * 4 + (threadIdx.x >> 6);
    if (row >= N_NODES) return;
    const bool active = lane < NCLASS;
    const int cl = active ? lane : (NCLASS - 1);
    const int lo = row_off[row], hi = row_off[row + 1];
    float acc = 0.f;
    int i = lo;
    for (; i + 7 < hi; i += 8) {
        int   s[8];
        float v[8];
#pragma unroll
        for (int j = 0; j < 8; ++j) { s[j] = src_s[i + j]; v[j] = val_s[i + j]; }
#pragma unroll
        for (int j = 0; j < 8; ++j)
            acc += v[j] * hw[(size_t)s[j] * NCLASS + cl];
    }
    for (; i < hi; ++i)
        acc += val_s[i] * hw[(size_t)src_s[i] * NCLASS + cl];

    float logit = acc + b2[cl];
    float m = active ? logit : -INFINITY;
#pragma unroll
    for (int o = 32; o > 0; o >>= 1) m = fmaxf(m, __shfl_xor(m, o));
    float ex = active ? expf(logit - m) : 0.f;
    float ssum = ex;
#pragma unroll
    for (int o = 32; o > 0; o >>= 1) ssum += __shfl_xor(ssum, o);
    if (active) out[(size_t)row * NCLASS + lane] = logit - m - logf(ssum);
}

// ---------------------------------------------------------------------------

extern "C" void kernel_launch(void* const* d_in, const int* in_sizes, int n_in,
                              void* d_out, int out_size, void* d_ws, size_t ws_size,
                              hipStream_t stream) {
    const float* x        = (const float*)d_in[0];
    const float* adj_vals = (const float*)d_in[1];
    const float* W1       = (const float*)d_in[2];
    const float* b1       = (const float*)d_in[3];
    const float* W2       = (const float*)d_in[4];
    const float* b2       = (const float*)d_in[5];
    const int*   src      = (const int*)d_in[6];
    const int*   dst      = (const int*)d_in[7];
    float* out = (float*)d_out;

    // Workspace layout (32.4 MB, proven present in round 8). hw aliases xw.
    // w1t (64 KB bf16 transposed W1) lives at the head of h's region: it is
    // only needed during gemm1, which completes before spmm1 writes h.
    const size_t OFF_H    = 12800000;            // h     : 50000*64 f32
    const size_t OFF_ROFF = 25600000;            // row_off: 50001 int
    const size_t OFF_CUR  = 25800016;            // counts/cursor : 50000 int
    const size_t OFF_SRC  = 26000016;            // src_s  : 800000 int
    const size_t OFF_VAL  = 29200016;            // val_s  : 800000 f32
    const size_t OFF_TS   = 32400016;            // tile_sums: NTILES int
    const size_t OFF_TO   = OFF_TS + NTILES * 4; // tile_off : NTILES int
    const size_t REQUIRED = OFF_TO + NTILES * 4; // 32,400,800 B
    if (ws_size < REQUIRED) return;              // refuse to write OOB

    char* ws = (char*)d_ws;
    float*          xw        = (float*)(ws);
    float*          hw        = (float*)(ws);    // alias (xw dead after spmm1)
    float*          h         = (float*)(ws + OFF_H);
    unsigned short* w1t       = (unsigned short*)(ws + OFF_H);  // dead before h written
    int*            row_off   = (int*)  (ws + OFF_ROFF);
    int*            counts    = (int*)  (ws + OFF_CUR);
    int*            src_s     = (int*)  (ws + OFF_SRC);
    float*          val_s     = (float*)(ws + OFF_VAL);
    int*            tile_sums = (int*)  (ws + OFF_TS);
    int*            tile_off  = (int*)  (ws + OFF_TO);

    // CSR build (ws poisoned 0xAA each call -> zero the counters first)
    zero_kernel<<<(N_NODES + 255) / 256, 256, 0, stream>>>(counts, N_NODES);
    hist_kernel<<<(N_EDGES + 255) / 256, 256, 0, stream>>>(dst, counts);
    tile_sum_kernel<<<NTILES, STILE, 0, stream>>>(counts, tile_sums);
    tile_scan_kernel<<<1, 128, 0, stream>>>(tile_sums, tile_off, row_off);
    tile_apply_kernel<<<NTILES, STILE, 0, stream>>>(counts, tile_off, row_off, counts);
    scatter_kernel<<<(N_EDGES + 255) / 256, 256, 0, stream>>>(dst, src, adj_vals,
                                                              counts, src_s, val_s);

    // Dense + sparse pipeline
    w1_bf16t_kernel<<<(NFEAT * NHID + 255) / 256, 256, 0, stream>>>(W1, w1t);
    gemm1_kernel<<<(N_NODES + 63) / 64, 256, 0, stream>>>(x, w1t, xw);
    spmm1_kernel<<<(N_NODES + 3) / 4, 256, 0, stream>>>(xw, src_s, val_s, row_off, b1, h);
    gemm2_kernel<<<(N_NODES + 63) / 64, 256, 0, stream>>>(h, W2, hw);
    spmm2_lsm_kernel<<<(N_NODES + 3) / 4, 256, 0, stream>>>(hw, src_s, val_s, row_off, b2, out);
}

// Round 10
// 385.457 us; speedup vs baseline: 1.5419x; 1.0071x over previous
//
#include <hip/hip_runtime.h>
#include <math.h>

#define N_NODES 50000
#define N_EDGES 800000
#define NFEAT   512
#define NHID    64
#define NCLASS  40

typedef __attribute__((ext_vector_type(8))) short bf16x8;   // 8 bf16 (4 VGPRs)
typedef __attribute__((ext_vector_type(4))) float f32x4;    // MFMA C/D

__device__ inline unsigned short f2bf(float f) {            // fp32 -> bf16 RNE
    unsigned int u = __float_as_uint(f);
    u += 0x7FFFu + ((u >> 16) & 1u);
    return (unsigned short)(u >> 16);
}

// ---------------------------------------------------------------------------
// CSR build: histogram of dst -> 3-phase multi-block exclusive scan ->
// scatter edge payload (src,val packed int2) into a dst-sorted array.
// Round 9: two separate 4B scattered stores gave 81.7 MB WRITE_SIZE (13x
// amplification); one 8B packed store halves lines touched.
// ---------------------------------------------------------------------------

#define STILE  512
#define NTILES ((N_NODES + STILE - 1) / STILE)   // 98

__global__ void zero_kernel(int* __restrict__ p, int n) {
    int i = blockIdx.x * blockDim.x + threadIdx.x;
    if (i < n) p[i] = 0;
}

__global__ void hist_kernel(const int* __restrict__ dst, int* __restrict__ counts) {
    int i = blockIdx.x * blockDim.x + threadIdx.x;
    if (i < N_EDGES) atomicAdd(&counts[dst[i]], 1);
}

__global__ __launch_bounds__(STILE) void tile_sum_kernel(const int* __restrict__ counts,
                                                         int* __restrict__ tile_sums) {
    __shared__ int wsum[STILE / 64];
    const int t = threadIdx.x, b = blockIdx.x;
    const int i = b * STILE + t;
    int v = (i < N_NODES) ? counts[i] : 0;
#pragma unroll
    for (int o = 32; o > 0; o >>= 1) v += __shfl_down(v, o);
    if ((t & 63) == 0) wsum[t >> 6] = v;
    __syncthreads();
    if (t < STILE / 64) {
        int s = wsum[t];
#pragma unroll
        for (int o = STILE / 128; o > 0; o >>= 1) s += __shfl_down(s, o);
        if (t == 0) tile_sums[b] = s;
    }
}

__global__ __launch_bounds__(128) void tile_scan_kernel(const int* __restrict__ tile_sums,
                                                        int* __restrict__ tile_off,
                                                        int* __restrict__ row_off) {
    __shared__ int lds[128];
    const int t = threadIdx.x;
    int v = (t < NTILES) ? tile_sums[t] : 0;
    lds[t] = v;
    __syncthreads();
    for (int off = 1; off < 128; off <<= 1) {
        int u = (t >= off) ? lds[t - off] : 0;
        __syncthreads();
        lds[t] += u;
        __syncthreads();
    }
    if (t < NTILES) tile_off[t] = lds[t] - v;
    if (t == 127) row_off[N_NODES] = lds[127];
}

__global__ __launch_bounds__(STILE) void tile_apply_kernel(const int* __restrict__ counts,
                                                           const int* __restrict__ tile_off,
                                                           int* __restrict__ row_off,
                                                           int* __restrict__ cursor) {
    __shared__ int lds[STILE];
    const int t = threadIdx.x, b = blockIdx.x;
    const int i = b * STILE + t;
    int v = (i < N_NODES) ? counts[i] : 0;
    lds[t] = v;
    __syncthreads();
    for (int off = 1; off < STILE; off <<= 1) {
        int u = (t >= off) ? lds[t - off] : 0;
        __syncthreads();
        lds[t] += u;
        __syncthreads();
    }
    if (i < N_NODES) {
        int excl = tile_off[b] + lds[t] - v;
        row_off[i] = excl;
        cursor[i]  = excl;
    }
}

__global__ void scatter_kernel(const int* __restrict__ dst,
                               const int* __restrict__ src,
                               const float* __restrict__ adj_vals,
                               int* __restrict__ cursor,
                               int2* __restrict__ ev_s) {
    int i = blockIdx.x * blockDim.x + threadIdx.x;
    if (i < N_EDGES) {
        int p = atomicAdd(&cursor[dst[i]], 1);
        ev_s[p] = make_int2(src[i], __float_as_int(adj_vals[i]));
    }
}

// ---------------------------------------------------------------------------
// W1 -> bf16, transposed: w1t[col][k] (64 x 512).
// ---------------------------------------------------------------------------
__global__ void w1_bf16t_kernel(const float* __restrict__ W1,
                                unsigned short* __restrict__ w1t) {
    int idx = blockIdx.x * blockDim.x + threadIdx.x;
    if (idx < NFEAT * NHID) {
        int k = idx >> 6, c = idx & 63;          // W1 is [k][c], c fastest
        w1t[(size_t)c * NFEAT + k] = f2bf(W1[idx]);
    }
}

// ---------------------------------------------------------------------------
// GEMM1 v4 (MFMA, LDS-free): xw = x @ W1. bf16 inputs, fp32 accumulate.
// Per K32-step: 2 coalesced float4 x-loads (+cvt), 4 x 16B w1t loads
// (L1-resident), 4 MFMAs. No LDS/barriers; x read once (HBM-bound ~20 us).
// Fragment maps (HW-verified m89/m120): A[m=lane&15][k=quad*8+j],
// B[k=quad*8+j][n=lane&15], D: col=lane&15, row=quad*4+reg.
// ---------------------------------------------------------------------------
__global__ __launch_bounds__(256) void gemm1_kernel(const float* __restrict__ x,
                                                    const unsigned short* __restrict__ w1t,
                                                    float* __restrict__ xw) {
    const int tid  = threadIdx.x;
    const int lane = tid & 63;
    const int wave = tid >> 6;
    const int i16  = lane & 15;
    const int quad = lane >> 4;

    const int arow = blockIdx.x * 64 + wave * 16 + i16;
    const int arc  = arow < N_NODES ? arow : N_NODES - 1;
    const float* xrow = x + (size_t)arc * NFEAT + quad * 8;

    const unsigned short* wbase = w1t + (size_t)i16 * NFEAT + quad * 8;

    f32x4 acc[4];
#pragma unroll
    for (int ct = 0; ct < 4; ++ct) acc[ct] = (f32x4){0.f, 0.f, 0.f, 0.f};

#pragma unroll 2
    for (int k0 = 0; k0 < NFEAT; k0 += 32) {
        float4 xa = *reinterpret_cast<const float4*>(xrow + k0);
        float4 xb = *reinterpret_cast<const float4*>(xrow + k0 + 4);
        bf16x8 a;
        a[0] = (short)f2bf(xa.x); a[1] = (short)f2bf(xa.y);
        a[2] = (short)f2bf(xa.z); a[3] = (short)f2bf(xa.w);
        a[4] = (short)f2bf(xb.x); a[5] = (short)f2bf(xb.y);
        a[6] = (short)f2bf(xb.z); a[7] = (short)f2bf(xb.w);
#pragma unroll
        for (int ct = 0; ct < 4; ++ct) {
            bf16x8 b = *reinterpret_cast<const bf16x8*>(wbase + (size_t)ct * 16 * NFEAT + k0);
            acc[ct] = __builtin_amdgcn_mfma_f32_16x16x32_bf16(a, b, acc[ct], 0, 0, 0);
        }
    }

    const int orow0 = blockIdx.x * 64 + wave * 16 + quad * 4;
#pragma unroll
    for (int reg = 0; reg < 4; ++reg) {
        int orow = orow0 + reg;
        if (orow < N_NODES) {
            float* op = xw + (size_t)orow * NHID + i16;
#pragma unroll
            for (int ct = 0; ct < 4; ++ct) op[ct * 16] = acc[ct][reg];
        }
    }
}

// ---------------------------------------------------------------------------
// SpMM1 + bias + relu. Wave per row, lane = feature. Sequential int2 edge
// stream + one gather per edge; unroll 8 for outstanding-gather depth.
// ---------------------------------------------------------------------------
__global__ void spmm1_kernel(const float* __restrict__ xw,
                             const int2* __restrict__ ev_s,
                             const int* __restrict__ row_off,
                             const float* __restrict__ b1,
                             float* __restrict__ h) {
    const int lane = threadIdx.x & 63;
    const int row  = blockIdx.x * 4 + (threadIdx.x >> 6);
    if (row >= N_NODES) return;
    const int lo = row_off[row], hi = row_off[row + 1];
    float acc = 0.f;
    int i = lo;
    for (; i + 7 < hi; i += 8) {
        int2 e[8];
#pragma unroll
        for (int j = 0; j < 8; ++j) e[j] = ev_s[i + j];
#pragma unroll
        for (int j = 0; j < 8; ++j)
            acc += __int_as_float(e[j].y) * xw[(size_t)e[j].x * NHID + lane];
    }
    for (; i < hi; ++i) {
        int2 e = ev_s[i];
        acc += __int_as_float(e.y) * xw[(size_t)e.x * NHID + lane];
    }
    h[(size_t)row * NHID + lane] = fmaxf(acc + b1[lane], 0.f);
}

// ---------------------------------------------------------------------------
// GEMM2 v2: hw = h @ W2. [50000,64] x [64,40]. LDS-tiled.
// ---------------------------------------------------------------------------
__global__ __launch_bounds__(256) void gemm2_kernel(const float* __restrict__ h,
                                                    const float* __restrict__ W2,
                                                    float* __restrict__ hw) {
    __shared__ float4 w2lds[16 * 40];    // 10 KB
    __shared__ float4 hlds[64 * 17];     // 17.4 KB
    const int tid  = threadIdx.x;
    const int lane = tid & 63;
    const int i16  = lane & 15;
    const int rg   = lane >> 4;
    const int wave = tid >> 6;
    const int i16c = (i16 < 10) ? i16 : 9;

    const int block_row0 = blockIdx.x * 64;

    for (int idx = tid; idx < 16 * 40; idx += 256) {
        int k0 = idx / 40, s = idx % 40;
        int c = s / 10, ig = s % 10;
        int col = 4 * ig + c;
        float4 v;
        v.x = W2[(4 * k0 + 0) * NCLASS + col];
        v.y = W2[(4 * k0 + 1) * NCLASS + col];
        v.z = W2[(4 * k0 + 2) * NCLASS + col];
        v.w = W2[(4 * k0 + 3) * NCLASS + col];
        w2lds[idx] = v;
    }
    for (int idx = tid; idx < 64 * 16; idx += 256) {
        int row = idx >> 4;
        int c4  = idx & 15;
        int gr  = block_row0 + row;
        if (gr > N_NODES - 1) gr = N_NODES - 1;
        hlds[row * 17 + c4] =
            *reinterpret_cast<const float4*>(h + (size_t)gr * NHID + 4 * c4);
    }
    __syncthreads();

    float acc[4][4];
#pragma unroll
    for (int r = 0; r < 4; ++r)
#pragma unroll
        for (int c = 0; c < 4; ++c) acc[r][c] = 0.f;

#pragma unroll
    for (int k0 = 0; k0 < 16; ++k0) {
        float4 wv[4];
#pragma unroll
        for (int c = 0; c < 4; ++c)
            wv[c] = w2lds[k0 * 40 + c * 10 + i16c];
        float4 xv[4];
#pragma unroll
        for (int r = 0; r < 4; ++r)
            xv[r] = hlds[(wave * 16 + rg * 4 + r) * 17 + k0];
#pragma unroll
        for (int r = 0; r < 4; ++r)
#pragma unroll
            for (int c = 0; c < 4; ++c)
                acc[r][c] = fmaf(xv[r].x, wv[c].x,
                            fmaf(xv[r].y, wv[c].y,
                            fmaf(xv[r].z, wv[c].z,
                            fmaf(xv[r].w, wv[c].w, acc[r][c]))));
    }

#pragma unroll
    for (int r = 0; r < 4; ++r) {
        int row = block_row0 + wave * 16 + rg * 4 + r;
        if (i16 < 10 && row < N_NODES) {
            float4 o; o.x = acc[r][0]; o.y = acc[r][1]; o.z = acc[r][2]; o.w = acc[r][3];
            *reinterpret_cast<float4*>(&hw[(size_t)row * NCLASS + 4 * i16]) = o;
        }
    }
}

// ---------------------------------------------------------------------------
// SpMM2 + b2 + log_softmax. Wave per row, lanes 0..39 = classes.
// ---------------------------------------------------------------------------
__global__ void spmm2_lsm_kernel(const float* __restrict__ hw,
                                 const int2* __restrict__ ev_s,
                                 const int* __restrict__ row_off,
                                 const float* __restrict__ b2,
                                 float* __restrict__ out) {
    const int lane = threadIdx.x & 63;
    const int row  = blockIdx.x * 4 + (threadIdx.x >> 6);
    if (row >= N_NODES) return;
    const bool active = lane < NCLASS;
    const int cl = active ? lane : (NCLASS - 1);
    const int lo = row_off[row], hi = row_off[row + 1];
    float acc = 0.f;
    int i = lo;
    for (; i + 7 < hi; i += 8) {
        int2 e[8];
#pragma unroll
        for (int j = 0; j < 8; ++j) e[j] = ev_s[i + j];
#pragma unroll
        for (int j = 0; j < 8; ++j)
            acc += __int_as_float(e[j].y) * hw[(size_t)e[j].x * NCLASS + cl];
    }
    for (; i < hi; ++i) {
        int2 e = ev_s[i];
        acc += __int_as_float(e.y) * hw[(size_t)e.x * NCLASS + cl];
    }

    float logit = acc + b2[cl];
    float m = active ? logit : -INFINITY;
#pragma unroll
    for (int o = 32; o > 0; o >>= 1) m = fmaxf(m, __shfl_xor(m, o));
    float ex = active ? expf(logit - m) : 0.f;
    float ssum = ex;
#pragma unroll
    for (int o = 32; o > 0; o >>= 1) ssum += __shfl_xor(ssum, o);
    if (active) out[(size_t)row * NCLASS + lane] = logit - m - logf(ssum);
}

// ---------------------------------------------------------------------------

extern "C" void kernel_launch(void* const* d_in, const int* in_sizes, int n_in,
                              void* d_out, int out_size, void* d_ws, size_t ws_size,
                              hipStream_t stream) {
    const float* x        = (const float*)d_in[0];
    const float* adj_vals = (const float*)d_in[1];
    const float* W1       = (const float*)d_in[2];
    const float* b1       = (const float*)d_in[3];
    const float* W2       = (const float*)d_in[4];
    const float* b2       = (const float*)d_in[5];
    const int*   src      = (const int*)d_in[6];
    const int*   dst      = (const int*)d_in[7];
    float* out = (float*)d_out;

    // Workspace layout (32.4 MB, proven present). hw aliases xw; w1t lives
    // at the head of h's region (dead before spmm1 writes h). ev_s (int2)
    // exactly replaces the old src_s+val_s pair.
    const size_t OFF_H    = 12800000;            // h     : 50000*64 f32
    const size_t OFF_ROFF = 25600000;            // row_off: 50001 int
    const size_t OFF_CUR  = 25800016;            // counts/cursor : 50000 int
    const size_t OFF_EV   = 26000016;            // ev_s  : 800000 int2 (8B-aligned)
    const size_t OFF_TS   = 32400016;            // tile_sums: NTILES int
    const size_t OFF_TO   = OFF_TS + NTILES * 4; // tile_off : NTILES int
    const size_t REQUIRED = OFF_TO + NTILES * 4; // 32,400,800 B
    if (ws_size < REQUIRED) return;              // refuse to write OOB

    char* ws = (char*)d_ws;
    float*          xw        = (float*)(ws);
    float*          hw        = (float*)(ws);    // alias (xw dead after spmm1)
    float*          h         = (float*)(ws + OFF_H);
    unsigned short* w1t       = (unsigned short*)(ws + OFF_H);
    int*            row_off   = (int*)  (ws + OFF_ROFF);
    int*            counts    = (int*)  (ws + OFF_CUR);
    int2*           ev_s      = (int2*) (ws + OFF_EV);
    int*            tile_sums = (int*)  (ws + OFF_TS);
    int*            tile_off  = (int*)  (ws + OFF_TO);

    // CSR build (ws poisoned 0xAA each call -> zero the counters first)
    zero_kernel<<<(N_NODES + 255) / 256, 256, 0, stream>>>(counts, N_NODES);
    hist_kernel<<<(N_EDGES + 255) / 256, 256, 0, stream>>>(dst, counts);
    tile_sum_kernel<<<NTILES, STILE, 0, stream>>>(counts, tile_sums);
    tile_scan_kernel<<<1, 128, 0, stream>>>(tile_sums, tile_off, row_off);
    tile_apply_kernel<<<NTILES, STILE, 0, stream>>>(counts, tile_off, row_off, counts);
    scatter_kernel<<<(N_EDGES + 255) / 256, 256, 0, stream>>>(dst, src, adj_vals,
                                                              counts, ev_s);

    // Dense + sparse pipeline
    w1_bf16t_kernel<<<(NFEAT * NHID + 255) / 256, 256, 0, stream>>>(W1, w1t);
    gemm1_kernel<<<(N_NODES + 63) / 64, 256, 0, stream>>>(x, w1t, xw);
    spmm1_kernel<<<(N_NODES + 3) / 4, 256, 0, stream>>>(xw, ev_s, row_off, b1, h);
    gemm2_kernel<<<(N_NODES + 63) / 64, 256, 0, stream>>>(h, W2, hw);
    spmm2_lsm_kernel<<<(N_NODES + 3) / 4, 256, 0, stream>>>(hw, ev_s, row_off, b2, out);
}